// Round 1
// baseline (885.880 us; speedup 1.0000x reference)
//
#include <hip/hip_runtime.h>

#define N_NODES 50000
#define N_EDGES 800000
#define HIDDEN  128
#define BN_EPS  1e-5f

// -------------------- scatter: one wave (64 lanes) per edge --------------------
// lane l handles features [2l, 2l+1]; atomicAdd into msg[dst]; lane0 bumps deg.
__global__ __launch_bounds__(256) void scatter_kernel(
    const float* __restrict__ h,
    const int* __restrict__ edge_index,
    float* __restrict__ msg,
    float* __restrict__ deg)
{
    const int* src = edge_index;
    const int* dst = edge_index + N_EDGES;
    const int lane = threadIdx.x & 63;
    const int waveInBlock = threadIdx.x >> 6;
    const int wavesPerBlock = blockDim.x >> 6;
    long long wave = (long long)blockIdx.x * wavesPerBlock + waveInBlock;
    const long long nWaves = (long long)gridDim.x * wavesPerBlock;

    for (long long e = wave; e < N_EDGES; e += nWaves) {
        const int s = src[e];
        const int d = dst[e];
        const float2 v = *reinterpret_cast<const float2*>(h + (size_t)s * HIDDEN + lane * 2);
        float* mrow = msg + (size_t)d * HIDDEN + lane * 2;
        atomicAdd(mrow,     v.x);
        atomicAdd(mrow + 1, v.y);
        if (lane == 0) atomicAdd(deg + d, 1.0f);
    }
}

// -------------------- fused dual GEMM: out = (msg/deg)@W_l^T + b_l + h@W_r^T ----
// Block: 128 rows x 128 cols, 256 threads (16x16), 8x8 micro-tile per thread.
// K = 256 (128 from agg via W_l, 128 from h via W_r), staged in 16-wide chunks.
#define BR 128
#define KC 16

__global__ __launch_bounds__(256) void gemm_kernel(
    const float* __restrict__ msg,
    const float* __restrict__ deg,
    const float* __restrict__ h,
    const float* __restrict__ W_l,
    const float* __restrict__ b_l,
    const float* __restrict__ W_r,
    float* __restrict__ out)
{
    __shared__ float Xs[KC][BR];       // [kk][row]
    __shared__ float Ws[KC][HIDDEN];   // [kk][col]
    __shared__ float invdeg[BR];

    const int tid = threadIdx.x;
    const int row0 = blockIdx.x * BR;

    if (tid < BR) {
        int r = row0 + tid;
        float dg = (r < N_NODES) ? deg[r] : 1.0f;
        invdeg[tid] = 1.0f / fmaxf(dg, 1.0f);
    }
    __syncthreads();

    const int ty = tid >> 4;       // 0..15 -> rows ty*8..ty*8+7
    const int tx = tid & 15;       // 0..15 -> cols tx*8..tx*8+7

    float acc[8][8];
#pragma unroll
    for (int i = 0; i < 8; i++)
#pragma unroll
        for (int j = 0; j < 8; j++) acc[i][j] = 0.0f;

    const int lrow  = tid >> 1;        // 0..127 (row for X stage / col for W stage)
    const int khalf = (tid & 1) * 8;   // 0 or 8

    for (int kc = 0; kc < 2 * HIDDEN; kc += KC) {
        // ---- stage X chunk: Xs[kk][row] ----
        {
            const int r = row0 + lrow;
            float xv[8];
            if (kc < HIDDEN) {
                const int kbase = kc + khalf;
                if (r < N_NODES) {
                    const float idg = invdeg[lrow];
                    const float4* p = reinterpret_cast<const float4*>(msg + (size_t)r * HIDDEN + kbase);
                    float4 a = p[0], b = p[1];
                    xv[0] = a.x * idg; xv[1] = a.y * idg; xv[2] = a.z * idg; xv[3] = a.w * idg;
                    xv[4] = b.x * idg; xv[5] = b.y * idg; xv[6] = b.z * idg; xv[7] = b.w * idg;
                } else {
#pragma unroll
                    for (int j = 0; j < 8; j++) xv[j] = 0.0f;
                }
            } else {
                const int kbase = (kc - HIDDEN) + khalf;
                if (r < N_NODES) {
                    const float4* p = reinterpret_cast<const float4*>(h + (size_t)r * HIDDEN + kbase);
                    float4 a = p[0], b = p[1];
                    xv[0] = a.x; xv[1] = a.y; xv[2] = a.z; xv[3] = a.w;
                    xv[4] = b.x; xv[5] = b.y; xv[6] = b.z; xv[7] = b.w;
                } else {
#pragma unroll
                    for (int j = 0; j < 8; j++) xv[j] = 0.0f;
                }
            }
#pragma unroll
            for (int j = 0; j < 8; j++) Xs[khalf + j][lrow] = xv[j];
        }
        // ---- stage W chunk: Ws[kk][col] = W[col][k] ----
        {
            const int col = lrow;
            const float* W = (kc < HIDDEN) ? W_l : W_r;
            const int kbase = (kc & (HIDDEN - 1)) + khalf;
            const float4* p = reinterpret_cast<const float4*>(W + (size_t)col * HIDDEN + kbase);
            float4 a = p[0], b = p[1];
            Ws[khalf + 0][col] = a.x; Ws[khalf + 1][col] = a.y;
            Ws[khalf + 2][col] = a.z; Ws[khalf + 3][col] = a.w;
            Ws[khalf + 4][col] = b.x; Ws[khalf + 5][col] = b.y;
            Ws[khalf + 6][col] = b.z; Ws[khalf + 7][col] = b.w;
        }
        __syncthreads();

#pragma unroll
        for (int kk = 0; kk < KC; kk++) {
            float a[8], b[8];
            float4 a0 = *reinterpret_cast<const float4*>(&Xs[kk][ty * 8]);
            float4 a1 = *reinterpret_cast<const float4*>(&Xs[kk][ty * 8 + 4]);
            float4 b0 = *reinterpret_cast<const float4*>(&Ws[kk][tx * 8]);
            float4 b1 = *reinterpret_cast<const float4*>(&Ws[kk][tx * 8 + 4]);
            a[0] = a0.x; a[1] = a0.y; a[2] = a0.z; a[3] = a0.w;
            a[4] = a1.x; a[5] = a1.y; a[6] = a1.z; a[7] = a1.w;
            b[0] = b0.x; b[1] = b0.y; b[2] = b0.z; b[3] = b0.w;
            b[4] = b1.x; b[5] = b1.y; b[6] = b1.z; b[7] = b1.w;
#pragma unroll
            for (int i = 0; i < 8; i++)
#pragma unroll
                for (int j = 0; j < 8; j++)
                    acc[i][j] += a[i] * b[j];
        }
        __syncthreads();
    }

    // epilogue: add bias, store pre-BN activations to out
    float4 bb0 = *reinterpret_cast<const float4*>(&b_l[tx * 8]);
    float4 bb1 = *reinterpret_cast<const float4*>(&b_l[tx * 8 + 4]);
#pragma unroll
    for (int i = 0; i < 8; i++) {
        int r = row0 + ty * 8 + i;
        if (r < N_NODES) {
            float4 o0, o1;
            o0.x = acc[i][0] + bb0.x; o0.y = acc[i][1] + bb0.y;
            o0.z = acc[i][2] + bb0.z; o0.w = acc[i][3] + bb0.w;
            o1.x = acc[i][4] + bb1.x; o1.y = acc[i][5] + bb1.y;
            o1.z = acc[i][6] + bb1.z; o1.w = acc[i][7] + bb1.w;
            float* op = out + (size_t)r * HIDDEN + tx * 8;
            *reinterpret_cast<float4*>(op)     = o0;
            *reinterpret_cast<float4*>(op + 4) = o1;
        }
    }
}

// -------------------- BN column stats (sum, sumsq) --------------------
__global__ __launch_bounds__(256) void bn_stats_kernel(
    const float* __restrict__ out,
    float* __restrict__ bn_sum,
    float* __restrict__ bn_sumsq)
{
    const int col  = threadIdx.x & (HIDDEN - 1);
    const int half = threadIdx.x >> 7;  // 0/1
    float s = 0.0f, s2 = 0.0f;
    for (int r = blockIdx.x * 2 + half; r < N_NODES; r += gridDim.x * 2) {
        float v = out[(size_t)r * HIDDEN + col];
        s += v;
        s2 += v * v;
    }
    atomicAdd(&bn_sum[col], s);
    atomicAdd(&bn_sumsq[col], s2);
}

// -------------------- BN apply + ReLU + residual --------------------
__global__ __launch_bounds__(256) void bn_apply_kernel(
    const float* __restrict__ h,
    const float* __restrict__ gamma,
    const float* __restrict__ beta,
    const float* __restrict__ bn_sum,
    const float* __restrict__ bn_sumsq,
    float* __restrict__ out)
{
    const float inv_n = 1.0f / (float)N_NODES;
    const size_t total = (size_t)N_NODES * HIDDEN;
    size_t idx = ((size_t)blockIdx.x * blockDim.x + threadIdx.x) * 4;
    const size_t stride = (size_t)gridDim.x * blockDim.x * 4;

    for (; idx < total; idx += stride) {
        const int col = (int)(idx & (HIDDEN - 1));
        float4 x  = *reinterpret_cast<float4*>(out + idx);
        float4 sm = *reinterpret_cast<const float4*>(bn_sum + col);
        float4 sq = *reinterpret_cast<const float4*>(bn_sumsq + col);
        float4 g  = *reinterpret_cast<const float4*>(gamma + col);
        float4 bt = *reinterpret_cast<const float4*>(beta + col);
        float4 hr = *reinterpret_cast<const float4*>(h + idx);

        float4 res;
        {
            float m = sm.x * inv_n; float var = sq.x * inv_n - m * m;
            float rs = rsqrtf(var + BN_EPS);
            float v = g.x * (x.x - m) * rs + bt.x;
            res.x = fmaxf(v, 0.0f) + hr.x;
        }
        {
            float m = sm.y * inv_n; float var = sq.y * inv_n - m * m;
            float rs = rsqrtf(var + BN_EPS);
            float v = g.y * (x.y - m) * rs + bt.y;
            res.y = fmaxf(v, 0.0f) + hr.y;
        }
        {
            float m = sm.z * inv_n; float var = sq.z * inv_n - m * m;
            float rs = rsqrtf(var + BN_EPS);
            float v = g.z * (x.z - m) * rs + bt.z;
            res.z = fmaxf(v, 0.0f) + hr.z;
        }
        {
            float m = sm.w * inv_n; float var = sq.w * inv_n - m * m;
            float rs = rsqrtf(var + BN_EPS);
            float v = g.w * (x.w - m) * rs + bt.w;
            res.w = fmaxf(v, 0.0f) + hr.w;
        }
        *reinterpret_cast<float4*>(out + idx) = res;
    }
}

extern "C" void kernel_launch(void* const* d_in, const int* in_sizes, int n_in,
                              void* d_out, int out_size, void* d_ws, size_t ws_size,
                              hipStream_t stream)
{
    const float* h          = (const float*)d_in[0];
    const int*   edge_index = (const int*)d_in[1];
    const float* W_l        = (const float*)d_in[2];
    const float* b_l        = (const float*)d_in[3];
    const float* W_r        = (const float*)d_in[4];
    const float* gamma      = (const float*)d_in[5];
    const float* beta       = (const float*)d_in[6];
    float* out = (float*)d_out;

    char* ws = (char*)d_ws;
    float* msg     = (float*)ws;                                    // N_NODES*HIDDEN
    float* deg     = (float*)(ws + (size_t)N_NODES * HIDDEN * 4);   // N_NODES
    float* bn_sum  = deg + N_NODES;                                 // HIDDEN
    float* bn_sumsq = bn_sum + HIDDEN;                              // HIDDEN

    const size_t zero_bytes = (size_t)N_NODES * HIDDEN * 4 + (size_t)N_NODES * 4
                            + 2 * HIDDEN * 4;
    hipMemsetAsync(d_ws, 0, zero_bytes, stream);

    scatter_kernel<<<4096, 256, 0, stream>>>(h, edge_index, msg, deg);

    const int gemm_blocks = (N_NODES + BR - 1) / BR;  // 391
    gemm_kernel<<<gemm_blocks, 256, 0, stream>>>(msg, deg, h, W_l, b_l, W_r, out);

    bn_stats_kernel<<<256, 256, 0, stream>>>(out, bn_sum, bn_sumsq);

    bn_apply_kernel<<<2048, 256, 0, stream>>>(h, gamma, beta, bn_sum, bn_sumsq, out);
}

// Round 2
// 293.721 us; speedup vs baseline: 3.0161x; 3.0161x over previous
//
#include <hip/hip_runtime.h>

#define N_NODES 50000
#define N_EDGES 800000
#define HIDDEN  128
#define BN_EPS  1e-5f
#define SLOT    128   // padded slots per node; Poisson(16) max deg << 128

// -------------------- bin: one thread per edge, int atomic on counter ---------
__global__ __launch_bounds__(256) void bin_kernel(
    const int* __restrict__ edge_index,
    int* __restrict__ cnt,
    int* __restrict__ slots)
{
    const int* src = edge_index;
    const int* dst = edge_index + N_EDGES;
    int e = blockIdx.x * blockDim.x + threadIdx.x;
    const int stride = gridDim.x * blockDim.x;
    for (; e < N_EDGES; e += stride) {
        const int d = dst[e];
        const int s = src[e];
        const int pos = atomicAdd(&cnt[d], 1);
        if (pos < SLOT) slots[(size_t)d * SLOT + pos] = s;
    }
}

// -------------------- gather: one wave per node, coalesced row reads ----------
__global__ __launch_bounds__(256) void gather_kernel(
    const float* __restrict__ h,
    const int* __restrict__ cnt,
    const int* __restrict__ slots,
    float* __restrict__ agg)
{
    const int lane = threadIdx.x & 63;
    const int wave = (blockIdx.x * blockDim.x + threadIdx.x) >> 6;
    if (wave >= N_NODES) return;
    const int n = wave;

    int c = cnt[n];
    c = (c > SLOT) ? SLOT : c;
    const int* sl = slots + (size_t)n * SLOT;
    const int fo = lane * 2;

    float2 acc = make_float2(0.0f, 0.0f);
    int j = 0;
    for (; j + 4 <= c; j += 4) {
        const int s0 = sl[j], s1 = sl[j + 1], s2 = sl[j + 2], s3 = sl[j + 3];
        const float2 v0 = *reinterpret_cast<const float2*>(h + (size_t)s0 * HIDDEN + fo);
        const float2 v1 = *reinterpret_cast<const float2*>(h + (size_t)s1 * HIDDEN + fo);
        const float2 v2 = *reinterpret_cast<const float2*>(h + (size_t)s2 * HIDDEN + fo);
        const float2 v3 = *reinterpret_cast<const float2*>(h + (size_t)s3 * HIDDEN + fo);
        acc.x += v0.x + v1.x + v2.x + v3.x;
        acc.y += v0.y + v1.y + v2.y + v3.y;
    }
    for (; j < c; j++) {
        const int s0 = sl[j];
        const float2 v0 = *reinterpret_cast<const float2*>(h + (size_t)s0 * HIDDEN + fo);
        acc.x += v0.x;
        acc.y += v0.y;
    }
    const float inv = 1.0f / (float)((c > 0) ? c : 1);
    acc.x *= inv;
    acc.y *= inv;
    *reinterpret_cast<float2*>(agg + (size_t)n * HIDDEN + fo) = acc;
}

// -------------------- fused dual GEMM: out = agg@W_l^T + b_l + h@W_r^T --------
#define BR 128
#define KC 16

__global__ __launch_bounds__(256) void gemm_kernel(
    const float* __restrict__ agg,
    const float* __restrict__ h,
    const float* __restrict__ W_l,
    const float* __restrict__ b_l,
    const float* __restrict__ W_r,
    float* __restrict__ out)
{
    __shared__ float Xs[KC][BR];       // [kk][row]
    __shared__ float Ws[KC][HIDDEN];   // [kk][col]

    const int tid = threadIdx.x;
    const int row0 = blockIdx.x * BR;

    const int ty = tid >> 4;       // 0..15 -> rows ty*8..ty*8+7
    const int tx = tid & 15;       // 0..15 -> cols tx*8..tx*8+7

    float acc[8][8];
#pragma unroll
    for (int i = 0; i < 8; i++)
#pragma unroll
        for (int j = 0; j < 8; j++) acc[i][j] = 0.0f;

    const int lrow  = tid >> 1;        // 0..127
    const int khalf = (tid & 1) * 8;   // 0 or 8

    for (int kc = 0; kc < 2 * HIDDEN; kc += KC) {
        // ---- stage X chunk ----
        {
            const int r = row0 + lrow;
            const float* X = (kc < HIDDEN) ? agg : h;
            const int kbase = (kc & (HIDDEN - 1)) + khalf;
            float xv[8];
            if (r < N_NODES) {
                const float4* p = reinterpret_cast<const float4*>(X + (size_t)r * HIDDEN + kbase);
                float4 a = p[0], b = p[1];
                xv[0] = a.x; xv[1] = a.y; xv[2] = a.z; xv[3] = a.w;
                xv[4] = b.x; xv[5] = b.y; xv[6] = b.z; xv[7] = b.w;
            } else {
#pragma unroll
                for (int j = 0; j < 8; j++) xv[j] = 0.0f;
            }
#pragma unroll
            for (int j = 0; j < 8; j++) Xs[khalf + j][lrow] = xv[j];
        }
        // ---- stage W chunk: Ws[kk][col] = W[col][k] ----
        {
            const int col = lrow;
            const float* W = (kc < HIDDEN) ? W_l : W_r;
            const int kbase = (kc & (HIDDEN - 1)) + khalf;
            const float4* p = reinterpret_cast<const float4*>(W + (size_t)col * HIDDEN + kbase);
            float4 a = p[0], b = p[1];
            Ws[khalf + 0][col] = a.x; Ws[khalf + 1][col] = a.y;
            Ws[khalf + 2][col] = a.z; Ws[khalf + 3][col] = a.w;
            Ws[khalf + 4][col] = b.x; Ws[khalf + 5][col] = b.y;
            Ws[khalf + 6][col] = b.z; Ws[khalf + 7][col] = b.w;
        }
        __syncthreads();

#pragma unroll
        for (int kk = 0; kk < KC; kk++) {
            float a[8], b[8];
            float4 a0 = *reinterpret_cast<const float4*>(&Xs[kk][ty * 8]);
            float4 a1 = *reinterpret_cast<const float4*>(&Xs[kk][ty * 8 + 4]);
            float4 b0 = *reinterpret_cast<const float4*>(&Ws[kk][tx * 8]);
            float4 b1 = *reinterpret_cast<const float4*>(&Ws[kk][tx * 8 + 4]);
            a[0] = a0.x; a[1] = a0.y; a[2] = a0.z; a[3] = a0.w;
            a[4] = a1.x; a[5] = a1.y; a[6] = a1.z; a[7] = a1.w;
            b[0] = b0.x; b[1] = b0.y; b[2] = b0.z; b[3] = b0.w;
            b[4] = b1.x; b[5] = b1.y; b[6] = b1.z; b[7] = b1.w;
#pragma unroll
            for (int i = 0; i < 8; i++)
#pragma unroll
                for (int j = 0; j < 8; j++)
                    acc[i][j] += a[i] * b[j];
        }
        __syncthreads();
    }

    float4 bb0 = *reinterpret_cast<const float4*>(&b_l[tx * 8]);
    float4 bb1 = *reinterpret_cast<const float4*>(&b_l[tx * 8 + 4]);
#pragma unroll
    for (int i = 0; i < 8; i++) {
        int r = row0 + ty * 8 + i;
        if (r < N_NODES) {
            float4 o0, o1;
            o0.x = acc[i][0] + bb0.x; o0.y = acc[i][1] + bb0.y;
            o0.z = acc[i][2] + bb0.z; o0.w = acc[i][3] + bb0.w;
            o1.x = acc[i][4] + bb1.x; o1.y = acc[i][5] + bb1.y;
            o1.z = acc[i][6] + bb1.z; o1.w = acc[i][7] + bb1.w;
            float* op = out + (size_t)r * HIDDEN + tx * 8;
            *reinterpret_cast<float4*>(op)     = o0;
            *reinterpret_cast<float4*>(op + 4) = o1;
        }
    }
}

// -------------------- BN column stats (sum, sumsq) --------------------
__global__ __launch_bounds__(256) void bn_stats_kernel(
    const float* __restrict__ out,
    float* __restrict__ bn_sum,
    float* __restrict__ bn_sumsq)
{
    const int col  = threadIdx.x & (HIDDEN - 1);
    const int half = threadIdx.x >> 7;  // 0/1
    float s = 0.0f, s2 = 0.0f;
    for (int r = blockIdx.x * 2 + half; r < N_NODES; r += gridDim.x * 2) {
        float v = out[(size_t)r * HIDDEN + col];
        s += v;
        s2 += v * v;
    }
    atomicAdd(&bn_sum[col], s);
    atomicAdd(&bn_sumsq[col], s2);
}

// -------------------- BN apply + ReLU + residual --------------------
__global__ __launch_bounds__(256) void bn_apply_kernel(
    const float* __restrict__ h,
    const float* __restrict__ gamma,
    const float* __restrict__ beta,
    const float* __restrict__ bn_sum,
    const float* __restrict__ bn_sumsq,
    float* __restrict__ out)
{
    const float inv_n = 1.0f / (float)N_NODES;
    const size_t total = (size_t)N_NODES * HIDDEN;
    size_t idx = ((size_t)blockIdx.x * blockDim.x + threadIdx.x) * 4;
    const size_t stride = (size_t)gridDim.x * blockDim.x * 4;

    for (; idx < total; idx += stride) {
        const int col = (int)(idx & (HIDDEN - 1));
        float4 x  = *reinterpret_cast<float4*>(out + idx);
        float4 sm = *reinterpret_cast<const float4*>(bn_sum + col);
        float4 sq = *reinterpret_cast<const float4*>(bn_sumsq + col);
        float4 g  = *reinterpret_cast<const float4*>(gamma + col);
        float4 bt = *reinterpret_cast<const float4*>(beta + col);
        float4 hr = *reinterpret_cast<const float4*>(h + idx);

        float4 res;
        {
            float m = sm.x * inv_n; float var = sq.x * inv_n - m * m;
            float rs = rsqrtf(var + BN_EPS);
            float v = g.x * (x.x - m) * rs + bt.x;
            res.x = fmaxf(v, 0.0f) + hr.x;
        }
        {
            float m = sm.y * inv_n; float var = sq.y * inv_n - m * m;
            float rs = rsqrtf(var + BN_EPS);
            float v = g.y * (x.y - m) * rs + bt.y;
            res.y = fmaxf(v, 0.0f) + hr.y;
        }
        {
            float m = sm.z * inv_n; float var = sq.z * inv_n - m * m;
            float rs = rsqrtf(var + BN_EPS);
            float v = g.z * (x.z - m) * rs + bt.z;
            res.z = fmaxf(v, 0.0f) + hr.z;
        }
        {
            float m = sm.w * inv_n; float var = sq.w * inv_n - m * m;
            float rs = rsqrtf(var + BN_EPS);
            float v = g.w * (x.w - m) * rs + bt.w;
            res.w = fmaxf(v, 0.0f) + hr.w;
        }
        *reinterpret_cast<float4*>(out + idx) = res;
    }
}

extern "C" void kernel_launch(void* const* d_in, const int* in_sizes, int n_in,
                              void* d_out, int out_size, void* d_ws, size_t ws_size,
                              hipStream_t stream)
{
    const float* h          = (const float*)d_in[0];
    const int*   edge_index = (const int*)d_in[1];
    const float* W_l        = (const float*)d_in[2];
    const float* b_l        = (const float*)d_in[3];
    const float* W_r        = (const float*)d_in[4];
    const float* gamma      = (const float*)d_in[5];
    const float* beta       = (const float*)d_in[6];
    float* out = (float*)d_out;

    char* ws = (char*)d_ws;
    int*   cnt      = (int*)ws;                                  // N_NODES
    int*   slots    = cnt + N_NODES;                             // N_NODES*SLOT
    float* agg      = (float*)(slots + (size_t)N_NODES * SLOT);  // N_NODES*HIDDEN
    float* bn_sum   = agg + (size_t)N_NODES * HIDDEN;            // HIDDEN
    float* bn_sumsq = bn_sum + HIDDEN;                           // HIDDEN

    // zero only counters + bn accumulators (slots/agg fully overwritten)
    hipMemsetAsync(cnt, 0, (size_t)N_NODES * sizeof(int), stream);
    hipMemsetAsync(bn_sum, 0, 2 * HIDDEN * sizeof(float), stream);

    bin_kernel<<<2048, 256, 0, stream>>>(edge_index, cnt, slots);

    gather_kernel<<<(N_NODES + 3) / 4, 256, 0, stream>>>(h, cnt, slots, agg);

    const int gemm_blocks = (N_NODES + BR - 1) / BR;  // 391
    gemm_kernel<<<gemm_blocks, 256, 0, stream>>>(agg, h, W_l, b_l, W_r, out);

    bn_stats_kernel<<<512, 256, 0, stream>>>(out, bn_sum, bn_sumsq);

    bn_apply_kernel<<<2048, 256, 0, stream>>>(h, gamma, beta, bn_sum, bn_sumsq, out);
}

// Round 3
// 258.529 us; speedup vs baseline: 3.4266x; 1.1361x over previous
//
#include <hip/hip_runtime.h>

#define N_NODES 50000
#define N_EDGES 800000
#define HIDDEN  128
#define BN_EPS  1e-5f
#define SLOT    64    // padded slots per node; Poisson(16): P(deg>64) ~ 2e-18

// -------------------- bin: one thread per edge, int atomic on counter ---------
// block 0 also zeroes the 256 floats of bn_sum/bn_sumsq (contiguous).
__global__ __launch_bounds__(256) void bin_kernel(
    const int* __restrict__ edge_index,
    int* __restrict__ cnt,
    int* __restrict__ slots,
    float* __restrict__ bn_acc)   // bn_sum[128] ++ bn_sumsq[128]
{
    if (blockIdx.x == 0) bn_acc[threadIdx.x] = 0.0f;

    const int* src = edge_index;
    const int* dst = edge_index + N_EDGES;
    const int e = blockIdx.x * blockDim.x + threadIdx.x;
    if (e < N_EDGES) {
        const int d = dst[e];
        const int s = src[e];
        const int pos = atomicAdd(&cnt[d], 1);
        if (pos < SLOT) slots[(size_t)d * SLOT + pos] = s;
    }
}

// -------------------- gather: one wave per node, coalesced row reads ----------
__global__ __launch_bounds__(256) void gather_kernel(
    const float* __restrict__ h,
    const int* __restrict__ cnt,
    const int* __restrict__ slots,
    float* __restrict__ agg)
{
    const int lane = threadIdx.x & 63;
    const int wave = (blockIdx.x * blockDim.x + threadIdx.x) >> 6;
    if (wave >= N_NODES) return;
    const int n = wave;

    int c = cnt[n];
    c = (c > SLOT) ? SLOT : c;
    const int* sl = slots + (size_t)n * SLOT;
    const int fo = lane * 2;

    float2 acc = make_float2(0.0f, 0.0f);
    int j = 0;
    for (; j + 8 <= c; j += 8) {
        int s0 = sl[j], s1 = sl[j+1], s2 = sl[j+2], s3 = sl[j+3];
        int s4 = sl[j+4], s5 = sl[j+5], s6 = sl[j+6], s7 = sl[j+7];
        float2 v0 = *reinterpret_cast<const float2*>(h + (size_t)s0 * HIDDEN + fo);
        float2 v1 = *reinterpret_cast<const float2*>(h + (size_t)s1 * HIDDEN + fo);
        float2 v2 = *reinterpret_cast<const float2*>(h + (size_t)s2 * HIDDEN + fo);
        float2 v3 = *reinterpret_cast<const float2*>(h + (size_t)s3 * HIDDEN + fo);
        float2 v4 = *reinterpret_cast<const float2*>(h + (size_t)s4 * HIDDEN + fo);
        float2 v5 = *reinterpret_cast<const float2*>(h + (size_t)s5 * HIDDEN + fo);
        float2 v6 = *reinterpret_cast<const float2*>(h + (size_t)s6 * HIDDEN + fo);
        float2 v7 = *reinterpret_cast<const float2*>(h + (size_t)s7 * HIDDEN + fo);
        acc.x += (v0.x + v1.x) + (v2.x + v3.x) + ((v4.x + v5.x) + (v6.x + v7.x));
        acc.y += (v0.y + v1.y) + (v2.y + v3.y) + ((v4.y + v5.y) + (v6.y + v7.y));
    }
    for (; j < c; j++) {
        const int s0 = sl[j];
        const float2 v0 = *reinterpret_cast<const float2*>(h + (size_t)s0 * HIDDEN + fo);
        acc.x += v0.x;
        acc.y += v0.y;
    }
    const float inv = 1.0f / (float)((c > 0) ? c : 1);
    acc.x *= inv;
    acc.y *= inv;
    *reinterpret_cast<float2*>(agg + (size_t)n * HIDDEN + fo) = acc;
}

// ---------- fused dual GEMM + BN-stat reduction -------------------------------
// out = agg@W_l^T + b_l + h@W_r^T ; also atomically accumulates per-column
// sum / sumsq of out into bn_acc.
// Tile: 64 rows x 128 cols, 256 threads, micro 4x8 in conflict-free quads
// (cols tx*4 and 64+tx*4 -> 16-lane f4 reads at 16B stride = 2-way = free).
#define BR 64
#define BC 128
#define KC 16

__global__ __launch_bounds__(256) void gemm_kernel(
    const float* __restrict__ agg,
    const float* __restrict__ h,
    const float* __restrict__ W_l,
    const float* __restrict__ b_l,
    const float* __restrict__ W_r,
    float* __restrict__ out,
    float* __restrict__ bn_acc)   // [0..127]=sum, [128..255]=sumsq
{
    __shared__ float Xs[KC][BR];    // 4 KB
    __shared__ float Ws[KC][BC];    // 8 KB
    __shared__ float red[16][BC];   // 8 KB

    const int tid  = threadIdx.x;
    const int row0 = blockIdx.x * BR;
    const int ty = tid >> 4;        // 0..15 -> rows ty*4..ty*4+3
    const int tx = tid & 15;        // cols tx*4..+3 and 64+tx*4..+3

    float acc[4][8];
#pragma unroll
    for (int i = 0; i < 4; i++)
#pragma unroll
        for (int j = 0; j < 8; j++) acc[i][j] = 0.0f;

    // staging maps
    const int srow = tid >> 2;         // 0..63
    const int sq   = (tid & 3) * 4;    // k sub-offset 0,4,8,12
    const int wcol = tid >> 1;         // 0..127
    const int wq   = (tid & 1) * 8;    // 0 or 8

    for (int kc = 0; kc < 2 * HIDDEN; kc += KC) {
        const float* X = (kc < HIDDEN) ? agg : h;
        const float* W = (kc < HIDDEN) ? W_l : W_r;
        const int kb = (kc & (HIDDEN - 1));

        // ---- stage X: Xs[kk][row] ----
        {
            const int r = row0 + srow;
            float4 v = make_float4(0.f, 0.f, 0.f, 0.f);
            if (r < N_NODES)
                v = *reinterpret_cast<const float4*>(X + (size_t)r * HIDDEN + kb + sq);
            Xs[sq + 0][srow] = v.x; Xs[sq + 1][srow] = v.y;
            Xs[sq + 2][srow] = v.z; Xs[sq + 3][srow] = v.w;
        }
        // ---- stage W: Ws[kk][col] = W[col][k] ----
        {
            const float4* p = reinterpret_cast<const float4*>(W + (size_t)wcol * HIDDEN + kb + wq);
            float4 a = p[0], b = p[1];
            Ws[wq + 0][wcol] = a.x; Ws[wq + 1][wcol] = a.y;
            Ws[wq + 2][wcol] = a.z; Ws[wq + 3][wcol] = a.w;
            Ws[wq + 4][wcol] = b.x; Ws[wq + 5][wcol] = b.y;
            Ws[wq + 6][wcol] = b.z; Ws[wq + 7][wcol] = b.w;
        }
        __syncthreads();

#pragma unroll
        for (int kk = 0; kk < KC; kk++) {
            float4 av = *reinterpret_cast<const float4*>(&Xs[kk][ty * 4]);
            float4 b0 = *reinterpret_cast<const float4*>(&Ws[kk][tx * 4]);
            float4 b1 = *reinterpret_cast<const float4*>(&Ws[kk][64 + tx * 4]);
            float a[4] = {av.x, av.y, av.z, av.w};
            float b[8] = {b0.x, b0.y, b0.z, b0.w, b1.x, b1.y, b1.z, b1.w};
#pragma unroll
            for (int i = 0; i < 4; i++)
#pragma unroll
                for (int j = 0; j < 8; j++)
                    acc[i][j] += a[i] * b[j];
        }
        __syncthreads();
    }

    // ---- epilogue: bias, store, per-column stats ----
    float4 bb0 = *reinterpret_cast<const float4*>(&b_l[tx * 4]);
    float4 bb1 = *reinterpret_cast<const float4*>(&b_l[64 + tx * 4]);
    float s[8], s2[8];
#pragma unroll
    for (int j = 0; j < 8; j++) { s[j] = 0.0f; s2[j] = 0.0f; }

#pragma unroll
    for (int i = 0; i < 4; i++) {
        const int r = row0 + ty * 4 + i;
        if (r < N_NODES) {
            float o[8];
            o[0] = acc[i][0] + bb0.x; o[1] = acc[i][1] + bb0.y;
            o[2] = acc[i][2] + bb0.z; o[3] = acc[i][3] + bb0.w;
            o[4] = acc[i][4] + bb1.x; o[5] = acc[i][5] + bb1.y;
            o[6] = acc[i][6] + bb1.z; o[7] = acc[i][7] + bb1.w;
            float* op = out + (size_t)r * HIDDEN;
            *reinterpret_cast<float4*>(op + tx * 4)      = make_float4(o[0], o[1], o[2], o[3]);
            *reinterpret_cast<float4*>(op + 64 + tx * 4) = make_float4(o[4], o[5], o[6], o[7]);
#pragma unroll
            for (int j = 0; j < 8; j++) { s[j] += o[j]; s2[j] += o[j] * o[j]; }
        }
    }

    // reduce sums over the block's 64 rows (16 ty groups), then atomic
#pragma unroll
    for (int j = 0; j < 4; j++) {
        red[ty][tx * 4 + j]      = s[j];
        red[ty][64 + tx * 4 + j] = s[4 + j];
    }
    __syncthreads();
    if (tid < BC) {
        float t = 0.0f;
#pragma unroll
        for (int y = 0; y < 16; y++) t += red[y][tid];
        atomicAdd(&bn_acc[tid], t);
    }
    __syncthreads();
#pragma unroll
    for (int j = 0; j < 4; j++) {
        red[ty][tx * 4 + j]      = s2[j];
        red[ty][64 + tx * 4 + j] = s2[4 + j];
    }
    __syncthreads();
    if (tid < BC) {
        float t = 0.0f;
#pragma unroll
        for (int y = 0; y < 16; y++) t += red[y][tid];
        atomicAdd(&bn_acc[BC + tid], t);
    }
}

// -------------------- BN apply + ReLU + residual --------------------
__global__ __launch_bounds__(256) void bn_apply_kernel(
    const float* __restrict__ h,
    const float* __restrict__ gamma,
    const float* __restrict__ beta,
    const float* __restrict__ bn_acc,
    float* __restrict__ out)
{
    const float inv_n = 1.0f / (float)N_NODES;
    const size_t total = (size_t)N_NODES * HIDDEN;
    size_t idx = ((size_t)blockIdx.x * blockDim.x + threadIdx.x) * 4;
    const size_t stride = (size_t)gridDim.x * blockDim.x * 4;

    for (; idx < total; idx += stride) {
        const int col = (int)(idx & (HIDDEN - 1));
        float4 x  = *reinterpret_cast<float4*>(out + idx);
        float4 sm = *reinterpret_cast<const float4*>(bn_acc + col);
        float4 sq = *reinterpret_cast<const float4*>(bn_acc + HIDDEN + col);
        float4 g  = *reinterpret_cast<const float4*>(gamma + col);
        float4 bt = *reinterpret_cast<const float4*>(beta + col);
        float4 hr = *reinterpret_cast<const float4*>(h + idx);

        float4 res;
        {
            float m = sm.x * inv_n; float var = sq.x * inv_n - m * m;
            float rs = rsqrtf(var + BN_EPS);
            float v = g.x * (x.x - m) * rs + bt.x;
            res.x = fmaxf(v, 0.0f) + hr.x;
        }
        {
            float m = sm.y * inv_n; float var = sq.y * inv_n - m * m;
            float rs = rsqrtf(var + BN_EPS);
            float v = g.y * (x.y - m) * rs + bt.y;
            res.y = fmaxf(v, 0.0f) + hr.y;
        }
        {
            float m = sm.z * inv_n; float var = sq.z * inv_n - m * m;
            float rs = rsqrtf(var + BN_EPS);
            float v = g.z * (x.z - m) * rs + bt.z;
            res.z = fmaxf(v, 0.0f) + hr.z;
        }
        {
            float m = sm.w * inv_n; float var = sq.w * inv_n - m * m;
            float rs = rsqrtf(var + BN_EPS);
            float v = g.w * (x.w - m) * rs + bt.w;
            res.w = fmaxf(v, 0.0f) + hr.w;
        }
        *reinterpret_cast<float4*>(out + idx) = res;
    }
}

extern "C" void kernel_launch(void* const* d_in, const int* in_sizes, int n_in,
                              void* d_out, int out_size, void* d_ws, size_t ws_size,
                              hipStream_t stream)
{
    const float* h          = (const float*)d_in[0];
    const int*   edge_index = (const int*)d_in[1];
    const float* W_l        = (const float*)d_in[2];
    const float* b_l        = (const float*)d_in[3];
    const float* W_r        = (const float*)d_in[4];
    const float* gamma      = (const float*)d_in[5];
    const float* beta       = (const float*)d_in[6];
    float* out = (float*)d_out;

    char* ws = (char*)d_ws;
    int*   cnt    = (int*)ws;                                   // N_NODES
    int*   slots  = cnt + N_NODES;                              // N_NODES*SLOT
    float* agg    = (float*)(slots + (size_t)N_NODES * SLOT);   // N_NODES*HIDDEN
    float* bn_acc = agg + (size_t)N_NODES * HIDDEN;             // 2*HIDDEN

    hipMemsetAsync(cnt, 0, (size_t)N_NODES * sizeof(int), stream);

    bin_kernel<<<(N_EDGES + 255) / 256, 256, 0, stream>>>(edge_index, cnt, slots, bn_acc);

    gather_kernel<<<(N_NODES + 3) / 4, 256, 0, stream>>>(h, cnt, slots, agg);

    const int gemm_blocks = (N_NODES + BR - 1) / BR;  // 782
    gemm_kernel<<<gemm_blocks, 256, 0, stream>>>(agg, h, W_l, b_l, W_r, out, bn_acc);

    bn_apply_kernel<<<2048, 256, 0, stream>>>(h, gamma, beta, bn_acc, out);
}

// Round 6
// 237.939 us; speedup vs baseline: 3.7231x; 1.0865x over previous
//
#include <hip/hip_runtime.h>

#define N_NODES 50000
#define N_EDGES 800000
#define HIDDEN  128
#define BN_EPS  1e-5f
#define SLOT    64    // Poisson(16): P(deg>64) ~ 1e-19 per node

typedef __attribute__((ext_vector_type(8))) short short8;
typedef __attribute__((ext_vector_type(4))) float f32x4;

// round-to-nearest-even fp32 -> bf16 bits
__device__ inline unsigned short f2bf(float x) {
    unsigned u = __float_as_uint(x);
    return (unsigned short)((u + 0x7FFFu + ((u >> 16) & 1u)) >> 16);
}
// split x into hi (bf16) + residual lo (bf16): x ~= hi + lo, err ~2^-18 rel
__device__ inline void cvt8(const float* x, short8& hi, short8& lo) {
#pragma unroll
    for (int i = 0; i < 8; i++) {
        unsigned u = __float_as_uint(x[i]);
        unsigned r = (u + 0x7FFFu + ((u >> 16) & 1u)) & 0xFFFF0000u;
        hi[i] = (short)(r >> 16);
        float res = x[i] - __uint_as_float(r);
        lo[i] = (short)f2bf(res);
    }
}

// ---- bin: 1 thread/edge int atomic; blocks 0-127 also convert W -> bf16 hi/lo
__global__ __launch_bounds__(256) void bin_kernel(
    const int* __restrict__ edge_index,
    const float* __restrict__ W_l,
    const float* __restrict__ W_r,
    int* __restrict__ cnt,
    int* __restrict__ slots,
    unsigned short* __restrict__ WhiG,   // [128 col][256 k] bf16
    unsigned short* __restrict__ WloG,
    float* __restrict__ bn_acc)
{
    const int gid = blockIdx.x * 256 + threadIdx.x;
    if (blockIdx.x < 128) {   // gid < 32768: W conversion, [n][k0..255] = Wl||Wr rows
        const int n = gid >> 8;
        const int k = gid & 255;
        const float w = (k < 128) ? W_l[n * 128 + k] : W_r[n * 128 + (k - 128)];
        unsigned u = __float_as_uint(w);
        unsigned r = (u + 0x7FFFu + ((u >> 16) & 1u)) & 0xFFFF0000u;
        WhiG[gid] = (unsigned short)(r >> 16);
        WloG[gid] = f2bf(w - __uint_as_float(r));
    }
    if (blockIdx.x == 128) bn_acc[threadIdx.x] = 0.0f;

    if (gid < N_EDGES) {
        const int d = edge_index[N_EDGES + gid];
        const int s = edge_index[gid];
        const int pos = atomicAdd(&cnt[d], 1);
        if (pos < SLOT) slots[(size_t)d * SLOT + pos] = s;
    }
}

// ---- gather: 2 nodes per wave (32 lanes x float4 each), coalesced row reads --
__global__ __launch_bounds__(256) void gather_kernel(
    const float* __restrict__ h,
    const int* __restrict__ cnt,
    const int* __restrict__ slots,
    float* __restrict__ agg)
{
    const int half = (threadIdx.x >> 5) & 1;    // which node within the wave
    const int sub  = threadIdx.x & 31;          // lane within half
    const int wave = (blockIdx.x * blockDim.x + threadIdx.x) >> 6;
    const int n = wave * 2 + half;
    if (n >= N_NODES) return;

    int c = cnt[n];
    c = (c > SLOT) ? SLOT : c;
    const int* sl = slots + (size_t)n * SLOT;
    const int fo = sub * 4;                     // 32 lanes x 4 floats = full row

    float4 acc = make_float4(0.0f, 0.0f, 0.0f, 0.0f);
    int j = 0;
    for (; j + 4 <= c; j += 4) {
        const int s0 = sl[j], s1 = sl[j + 1], s2 = sl[j + 2], s3 = sl[j + 3];
        const float4 v0 = *reinterpret_cast<const float4*>(h + (size_t)s0 * HIDDEN + fo);
        const float4 v1 = *reinterpret_cast<const float4*>(h + (size_t)s1 * HIDDEN + fo);
        const float4 v2 = *reinterpret_cast<const float4*>(h + (size_t)s2 * HIDDEN + fo);
        const float4 v3 = *reinterpret_cast<const float4*>(h + (size_t)s3 * HIDDEN + fo);
        acc.x += (v0.x + v1.x) + (v2.x + v3.x);
        acc.y += (v0.y + v1.y) + (v2.y + v3.y);
        acc.z += (v0.z + v1.z) + (v2.z + v3.z);
        acc.w += (v0.w + v1.w) + (v2.w + v3.w);
    }
    for (; j < c; j++) {
        const float4 v0 = *reinterpret_cast<const float4*>(h + (size_t)sl[j] * HIDDEN + fo);
        acc.x += v0.x; acc.y += v0.y; acc.z += v0.z; acc.w += v0.w;
    }
    const float inv = 1.0f / (float)((c > 0) ? c : 1);
    acc.x *= inv; acc.y *= inv; acc.z *= inv; acc.w *= inv;
    *reinterpret_cast<float4*>(agg + (size_t)n * HIDDEN + fo) = acc;
}

// ---- MFMA split-bf16 dual GEMM + fused BN stats -----------------------------
// out = agg@W_l^T + b_l + h@W_r^T  via  XhiWhi + XhiWlo + XloWhi (3-product).
// Block: 4 waves, 128 rows x 128 cols. Wave w: rows w*32..+31 (2x 16-row subs).
// K = 256 (agg:0-127 via W_l, h:128-255 via W_r), chunks of 64.
// X: per-lane direct global loads (zero reuse -> no LDS). W: LDS hi/lo,
// XOR slot-swizzle (slot^=col&7) -> <=2-way bank aliasing (free).
__global__ __launch_bounds__(256) void gemm_kernel(
    const float* __restrict__ agg,
    const float* __restrict__ h,
    const unsigned short* __restrict__ WhiG,   // [128][256]
    const unsigned short* __restrict__ WloG,
    const float* __restrict__ b_l,
    float* __restrict__ out,
    float* __restrict__ bn_acc)
{
    __shared__ short WsH[128][64];   // 16 KB  [col][k within chunk], swizzled slots
    __shared__ short WsL[128][64];   // 16 KB
    __shared__ float bnS[128];
    __shared__ float bnS2[128];

    const int tid  = threadIdx.x;
    const int lane = tid & 63;
    const int wv   = tid >> 6;
    const int row0 = blockIdx.x * 128;
    const int colb = lane & 15;      // MFMA col within 16-sub / A row within 16-sub
    const int quad = lane >> 4;      // k-window group

    if (tid < 128) { bnS[tid] = 0.0f; bnS2[tid] = 0.0f; }

    f32x4 acc[2][8];
#pragma unroll
    for (int s = 0; s < 2; s++)
#pragma unroll
        for (int c = 0; c < 8; c++) acc[s][c] = (f32x4)(0.0f);

    // staging map: thread -> col = tid>>1, slot-halves by tid&1
    const int wcol  = tid >> 1;
    const int sbase = (tid & 1) * 4;

    for (int kc = 0; kc < 4; kc++) {
        const float* X = (kc < 2) ? agg : h;
        const int kb = (kc & 1) * 64;      // k-offset within X's 128 cols
        const int kw = kc * 64;            // k-offset within W's 256 cols

        __syncthreads();   // protect LDS from previous chunk's readers
        // ---- stage W chunk (bf16 copy, swizzled) ----
#pragma unroll
        for (int j = 0; j < 4; j++) {
            const int slot = sbase + j;
            short8 vh = *reinterpret_cast<const short8*>(WhiG + (size_t)wcol * 256 + kw + slot * 8);
            short8 vl = *reinterpret_cast<const short8*>(WloG + (size_t)wcol * 256 + kw + slot * 8);
            const int sp = slot ^ (wcol & 7);
            *reinterpret_cast<short8*>(&WsH[wcol][sp * 8]) = vh;
            *reinterpret_cast<short8*>(&WsL[wcol][sp * 8]) = vl;
        }
        __syncthreads();

#pragma unroll
        for (int ks = 0; ks < 2; ks++) {
            // ---- load + split A fragments (2 row-subs) direct from global ----
            short8 ahi[2], alo[2];
#pragma unroll
            for (int sub = 0; sub < 2; sub++) {
                int row = row0 + wv * 32 + sub * 16 + colb;
                row = (row < N_NODES) ? row : (N_NODES - 1);
                const float* xp = X + (size_t)row * HIDDEN + kb + ks * 32 + quad * 8;
                float xr[8];
                const float4 p0 = *reinterpret_cast<const float4*>(xp);
                const float4 p1 = *reinterpret_cast<const float4*>(xp + 4);
                xr[0] = p0.x; xr[1] = p0.y; xr[2] = p0.z; xr[3] = p0.w;
                xr[4] = p1.x; xr[5] = p1.y; xr[6] = p1.z; xr[7] = p1.w;
                cvt8(xr, ahi[sub], alo[sub]);
            }
            // ---- MFMA over 8 col-subs x 3 products ----
#pragma unroll
            for (int c = 0; c < 8; c++) {
                const int bc = c * 16 + colb;
                const int sp = (ks * 4 + quad) ^ (bc & 7);
                short8 bhi = *reinterpret_cast<const short8*>(&WsH[bc][sp * 8]);
                short8 blo = *reinterpret_cast<const short8*>(&WsL[bc][sp * 8]);
#pragma unroll
                for (int sub = 0; sub < 2; sub++) {
                    acc[sub][c] = __builtin_amdgcn_mfma_f32_16x16x32_bf16(ahi[sub], bhi, acc[sub][c], 0, 0, 0);
                    acc[sub][c] = __builtin_amdgcn_mfma_f32_16x16x32_bf16(ahi[sub], blo, acc[sub][c], 0, 0, 0);
                    acc[sub][c] = __builtin_amdgcn_mfma_f32_16x16x32_bf16(alo[sub], bhi, acc[sub][c], 0, 0, 0);
                }
            }
        }
    }

    // ---- epilogue: bias add, store, fused BN column stats ----
    // D layout: col = lane&15 (+c*16), row = quad*4 + reg (+sub*16 + wv*32)
#pragma unroll
    for (int c = 0; c < 8; c++) {
        const int col = c * 16 + colb;
        const float bias = b_l[col];
        float s = 0.0f, s2 = 0.0f;
#pragma unroll
        for (int sub = 0; sub < 2; sub++) {
            const int rbase = row0 + wv * 32 + sub * 16 + quad * 4;
#pragma unroll
            for (int reg = 0; reg < 4; reg++) {
                const int r = rbase + reg;
                if (r < N_NODES) {
                    const float o = acc[sub][c][reg] + bias;
                    out[(size_t)r * HIDDEN + col] = o;
                    s += o; s2 += o * o;
                }
            }
        }
        atomicAdd(&bnS[col], s);
        atomicAdd(&bnS2[col], s2);
    }
    __syncthreads();
    if (tid < 128) {
        atomicAdd(&bn_acc[tid], bnS[tid]);
        atomicAdd(&bn_acc[128 + tid], bnS2[tid]);
    }
}

// ---- BN apply + ReLU + residual ----
__global__ __launch_bounds__(256) void bn_apply_kernel(
    const float* __restrict__ h,
    const float* __restrict__ gamma,
    const float* __restrict__ beta,
    const float* __restrict__ bn_acc,
    float* __restrict__ out)
{
    const float inv_n = 1.0f / (float)N_NODES;
    const size_t total = (size_t)N_NODES * HIDDEN;
    size_t idx = ((size_t)blockIdx.x * blockDim.x + threadIdx.x) * 4;
    const size_t stride = (size_t)gridDim.x * blockDim.x * 4;

    for (; idx < total; idx += stride) {
        const int col = (int)(idx & (HIDDEN - 1));
        float4 x  = *reinterpret_cast<float4*>(out + idx);
        float4 sm = *reinterpret_cast<const float4*>(bn_acc + col);
        float4 sq = *reinterpret_cast<const float4*>(bn_acc + HIDDEN + col);
        float4 g  = *reinterpret_cast<const float4*>(gamma + col);
        float4 bt = *reinterpret_cast<const float4*>(beta + col);
        float4 hr = *reinterpret_cast<const float4*>(h + idx);

        float4 res;
        {
            float m = sm.x * inv_n; float var = sq.x * inv_n - m * m;
            float v = g.x * (x.x - m) * rsqrtf(var + BN_EPS) + bt.x;
            res.x = fmaxf(v, 0.0f) + hr.x;
        }
        {
            float m = sm.y * inv_n; float var = sq.y * inv_n - m * m;
            float v = g.y * (x.y - m) * rsqrtf(var + BN_EPS) + bt.y;
            res.y = fmaxf(v, 0.0f) + hr.y;
        }
        {
            float m = sm.z * inv_n; float var = sq.z * inv_n - m * m;
            float v = g.z * (x.z - m) * rsqrtf(var + BN_EPS) + bt.z;
            res.z = fmaxf(v, 0.0f) + hr.z;
        }
        {
            float m = sm.w * inv_n; float var = sq.w * inv_n - m * m;
            float v = g.w * (x.w - m) * rsqrtf(var + BN_EPS) + bt.w;
            res.w = fmaxf(v, 0.0f) + hr.w;
        }
        *reinterpret_cast<float4*>(out + idx) = res;
    }
}

extern "C" void kernel_launch(void* const* d_in, const int* in_sizes, int n_in,
                              void* d_out, int out_size, void* d_ws, size_t ws_size,
                              hipStream_t stream)
{
    const float* h          = (const float*)d_in[0];
    const int*   edge_index = (const int*)d_in[1];
    const float* W_l        = (const float*)d_in[2];
    const float* b_l        = (const float*)d_in[3];
    const float* W_r        = (const float*)d_in[4];
    const float* gamma      = (const float*)d_in[5];
    const float* beta       = (const float*)d_in[6];
    float* out = (float*)d_out;

    char* ws = (char*)d_ws;
    int*   cnt   = (int*)ws;                                      // 50000
    int*   slots = cnt + N_NODES;                                 // 50000*64
    float* agg   = (float*)(slots + (size_t)N_NODES * SLOT);      // 50000*128
    unsigned short* WhiG = (unsigned short*)(agg + (size_t)N_NODES * HIDDEN);  // 32768 (16B-aligned)
    unsigned short* WloG = WhiG + 128 * 256;                      // 32768
    float* bn_acc = (float*)(WloG + 128 * 256);                   // 256

    hipMemsetAsync(cnt, 0, (size_t)N_NODES * sizeof(int), stream);

    bin_kernel<<<(N_EDGES + 255) / 256, 256, 0, stream>>>(
        edge_index, W_l, W_r, cnt, slots, WhiG, WloG, bn_acc);

    // 2 nodes per wave -> 25000 waves -> 6250 blocks of 4 waves
    gather_kernel<<<(N_NODES / 2 + 3) / 4, 256, 0, stream>>>(h, cnt, slots, agg);

    gemm_kernel<<<(N_NODES + 127) / 128, 256, 0, stream>>>(
        agg, h, WhiG, WloG, b_l, out, bn_acc);

    bn_apply_kernel<<<2048, 256, 0, stream>>>(h, gamma, beta, bn_acc, out);
}

// Round 7
// 235.182 us; speedup vs baseline: 3.7668x; 1.0117x over previous
//
#include <hip/hip_runtime.h>

#define N_NODES 50000
#define N_EDGES 800000
#define HIDDEN  128
#define BN_EPS  1e-5f
#define SLOT    64    // Poisson(16): P(deg>64) ~ 1e-19 per node

typedef __attribute__((ext_vector_type(8))) short short8;
typedef __attribute__((ext_vector_type(4))) float f32x4;

// round-to-nearest-even fp32 -> bf16 bits
__device__ inline unsigned short f2bf(float x) {
    unsigned u = __float_as_uint(x);
    return (unsigned short)((u + 0x7FFFu + ((u >> 16) & 1u)) >> 16);
}
// split x into hi (bf16) + residual lo (bf16): x ~= hi + lo, err ~2^-18 rel
__device__ inline void cvt8(const float* x, short8& hi, short8& lo) {
#pragma unroll
    for (int i = 0; i < 8; i++) {
        unsigned u = __float_as_uint(x[i]);
        unsigned r = (u + 0x7FFFu + ((u >> 16) & 1u)) & 0xFFFF0000u;
        hi[i] = (short)(r >> 16);
        float res = x[i] - __uint_as_float(r);
        lo[i] = (short)f2bf(res);
    }
}

// ---- bin: 1 thread/edge int atomic; blocks 0-127 also convert W -> bf16 hi/lo
__global__ __launch_bounds__(256) void bin_kernel(
    const int* __restrict__ edge_index,
    const float* __restrict__ W_l,
    const float* __restrict__ W_r,
    int* __restrict__ cnt,
    int* __restrict__ slots,
    unsigned short* __restrict__ WhiG,   // [128 col][256 k] bf16
    unsigned short* __restrict__ WloG,
    float* __restrict__ bn_acc)
{
    const int gid = blockIdx.x * 256 + threadIdx.x;
    if (blockIdx.x < 128) {   // gid < 32768: W conversion, [n][k0..255] = Wl||Wr rows
        const int n = gid >> 8;
        const int k = gid & 255;
        const float w = (k < 128) ? W_l[n * 128 + k] : W_r[n * 128 + (k - 128)];
        unsigned u = __float_as_uint(w);
        unsigned r = (u + 0x7FFFu + ((u >> 16) & 1u)) & 0xFFFF0000u;
        WhiG[gid] = (unsigned short)(r >> 16);
        WloG[gid] = f2bf(w - __uint_as_float(r));
    }
    if (blockIdx.x == 128) bn_acc[threadIdx.x] = 0.0f;

    if (gid < N_EDGES) {
        const int d = edge_index[N_EDGES + gid];
        const int s = edge_index[gid];
        const int pos = atomicAdd(&cnt[d], 1);
        if (pos < SLOT) slots[(size_t)d * SLOT + pos] = s;
    }
}

// ---- gather: feature-split 2-pass; wave = 4 nodes x 16 lanes x float4 --------
// Pass p reads only h[:, 64p:64p+64) -> 12.8 MB working set (vs 25.6) for
// better L2 residency. 12500 waves per pass, grid = 2 passes concatenated.
__global__ __launch_bounds__(256) void gather_kernel(
    const float* __restrict__ h,
    const int* __restrict__ cnt,
    const int* __restrict__ slots,
    float* __restrict__ agg)
{
    const int WPP = N_NODES / 4;                 // waves per pass = 12500
    const int gwave = (blockIdx.x * 256 + threadIdx.x) >> 6;
    const int pass = gwave / WPP;                // 0 or 1 (feature half)
    const int w    = gwave - pass * WPP;
    const int group = (threadIdx.x >> 4) & 3;    // node within wave
    const int sub   = threadIdx.x & 15;          // lane within group
    const int n  = w * 4 + group;                // < 50000 always
    const int fo = pass * 64 + sub * 4;

    int c = cnt[n];
    c = (c > SLOT) ? SLOT : c;
    const int* sl = slots + (size_t)n * SLOT;

    float4 acc = make_float4(0.0f, 0.0f, 0.0f, 0.0f);
    int j = 0;
    for (; j + 4 <= c; j += 4) {
        const int s0 = sl[j], s1 = sl[j + 1], s2 = sl[j + 2], s3 = sl[j + 3];
        const float4 v0 = *reinterpret_cast<const float4*>(h + (size_t)s0 * HIDDEN + fo);
        const float4 v1 = *reinterpret_cast<const float4*>(h + (size_t)s1 * HIDDEN + fo);
        const float4 v2 = *reinterpret_cast<const float4*>(h + (size_t)s2 * HIDDEN + fo);
        const float4 v3 = *reinterpret_cast<const float4*>(h + (size_t)s3 * HIDDEN + fo);
        acc.x += (v0.x + v1.x) + (v2.x + v3.x);
        acc.y += (v0.y + v1.y) + (v2.y + v3.y);
        acc.z += (v0.z + v1.z) + (v2.z + v3.z);
        acc.w += (v0.w + v1.w) + (v2.w + v3.w);
    }
    for (; j < c; j++) {
        const float4 v0 = *reinterpret_cast<const float4*>(h + (size_t)sl[j] * HIDDEN + fo);
        acc.x += v0.x; acc.y += v0.y; acc.z += v0.z; acc.w += v0.w;
    }
    const float inv = 1.0f / (float)((c > 0) ? c : 1);
    acc.x *= inv; acc.y *= inv; acc.z *= inv; acc.w *= inv;
    *reinterpret_cast<float4*>(agg + (size_t)n * HIDDEN + fo) = acc;
}

// ---- MFMA split-bf16 dual GEMM + fused BN stats -----------------------------
// out = agg@W_l^T + b_l + h@W_r^T  via  XhiWhi + XhiWlo + XloWhi (3-product).
// Block: 4 waves, 128 rows x 128 cols. Wave w: rows w*32..+31 (2x 16-row subs).
// K = 256 (agg:0-127 via W_l, h:128-255 via W_r), chunks of 64.
// X: per-lane direct global loads (zero reuse -> no LDS). W: LDS hi/lo,
// XOR slot-swizzle (slot^=col&7) -> <=2-way bank aliasing (free).
__global__ __launch_bounds__(256) void gemm_kernel(
    const float* __restrict__ agg,
    const float* __restrict__ h,
    const unsigned short* __restrict__ WhiG,   // [128][256]
    const unsigned short* __restrict__ WloG,
    const float* __restrict__ b_l,
    float* __restrict__ out,
    float* __restrict__ bn_acc)
{
    __shared__ short WsH[128][64];   // 16 KB  [col][k within chunk], swizzled slots
    __shared__ short WsL[128][64];   // 16 KB
    __shared__ float bnS[128];
    __shared__ float bnS2[128];

    const int tid  = threadIdx.x;
    const int lane = tid & 63;
    const int wv   = tid >> 6;
    const int row0 = blockIdx.x * 128;
    const int colb = lane & 15;      // MFMA col within 16-sub / A row within 16-sub
    const int quad = lane >> 4;      // k-window group

    if (tid < 128) { bnS[tid] = 0.0f; bnS2[tid] = 0.0f; }

    f32x4 acc[2][8];
#pragma unroll
    for (int s = 0; s < 2; s++)
#pragma unroll
        for (int c = 0; c < 8; c++) acc[s][c] = (f32x4)(0.0f);

    // staging map: thread -> col = tid>>1, slot-halves by tid&1
    const int wcol  = tid >> 1;
    const int sbase = (tid & 1) * 4;

    for (int kc = 0; kc < 4; kc++) {
        const float* X = (kc < 2) ? agg : h;
        const int kb = (kc & 1) * 64;      // k-offset within X's 128 cols
        const int kw = kc * 64;            // k-offset within W's 256 cols

        __syncthreads();   // protect LDS from previous chunk's readers
        // ---- stage W chunk (bf16 copy, swizzled) ----
#pragma unroll
        for (int j = 0; j < 4; j++) {
            const int slot = sbase + j;
            short8 vh = *reinterpret_cast<const short8*>(WhiG + (size_t)wcol * 256 + kw + slot * 8);
            short8 vl = *reinterpret_cast<const short8*>(WloG + (size_t)wcol * 256 + kw + slot * 8);
            const int sp = slot ^ (wcol & 7);
            *reinterpret_cast<short8*>(&WsH[wcol][sp * 8]) = vh;
            *reinterpret_cast<short8*>(&WsL[wcol][sp * 8]) = vl;
        }
        __syncthreads();

#pragma unroll
        for (int ks = 0; ks < 2; ks++) {
            // ---- load + split A fragments (2 row-subs) direct from global ----
            short8 ahi[2], alo[2];
#pragma unroll
            for (int sub = 0; sub < 2; sub++) {
                int row = row0 + wv * 32 + sub * 16 + colb;
                row = (row < N_NODES) ? row : (N_NODES - 1);
                const float* xp = X + (size_t)row * HIDDEN + kb + ks * 32 + quad * 8;
                float xr[8];
                const float4 p0 = *reinterpret_cast<const float4*>(xp);
                const float4 p1 = *reinterpret_cast<const float4*>(xp + 4);
                xr[0] = p0.x; xr[1] = p0.y; xr[2] = p0.z; xr[3] = p0.w;
                xr[4] = p1.x; xr[5] = p1.y; xr[6] = p1.z; xr[7] = p1.w;
                cvt8(xr, ahi[sub], alo[sub]);
            }
            // ---- MFMA over 8 col-subs x 3 products ----
#pragma unroll
            for (int c = 0; c < 8; c++) {
                const int bc = c * 16 + colb;
                const int sp = (ks * 4 + quad) ^ (bc & 7);
                short8 bhi = *reinterpret_cast<const short8*>(&WsH[bc][sp * 8]);
                short8 blo = *reinterpret_cast<const short8*>(&WsL[bc][sp * 8]);
#pragma unroll
                for (int sub = 0; sub < 2; sub++) {
                    acc[sub][c] = __builtin_amdgcn_mfma_f32_16x16x32_bf16(ahi[sub], bhi, acc[sub][c], 0, 0, 0);
                    acc[sub][c] = __builtin_amdgcn_mfma_f32_16x16x32_bf16(ahi[sub], blo, acc[sub][c], 0, 0, 0);
                    acc[sub][c] = __builtin_amdgcn_mfma_f32_16x16x32_bf16(alo[sub], bhi, acc[sub][c], 0, 0, 0);
                }
            }
        }
    }

    // ---- epilogue: bias add, store, fused BN column stats ----
    // D layout: col = lane&15 (+c*16), row = quad*4 + reg (+sub*16 + wv*32)
#pragma unroll
    for (int c = 0; c < 8; c++) {
        const int col = c * 16 + colb;
        const float bias = b_l[col];
        float s = 0.0f, s2 = 0.0f;
#pragma unroll
        for (int sub = 0; sub < 2; sub++) {
            const int rbase = row0 + wv * 32 + sub * 16 + quad * 4;
#pragma unroll
            for (int reg = 0; reg < 4; reg++) {
                const int r = rbase + reg;
                if (r < N_NODES) {
                    const float o = acc[sub][c][reg] + bias;
                    out[(size_t)r * HIDDEN + col] = o;
                    s += o; s2 += o * o;
                }
            }
        }
        atomicAdd(&bnS[col], s);
        atomicAdd(&bnS2[col], s2);
    }
    __syncthreads();
    if (tid < 128) {
        atomicAdd(&bn_acc[tid], bnS[tid]);
        atomicAdd(&bn_acc[128 + tid], bnS2[tid]);
    }
}

// ---- BN apply + ReLU + residual ----
__global__ __launch_bounds__(256) void bn_apply_kernel(
    const float* __restrict__ h,
    const float* __restrict__ gamma,
    const float* __restrict__ beta,
    const float* __restrict__ bn_acc,
    float* __restrict__ out)
{
    const float inv_n = 1.0f / (float)N_NODES;
    const size_t total = (size_t)N_NODES * HIDDEN;
    size_t idx = ((size_t)blockIdx.x * blockDim.x + threadIdx.x) * 4;
    const size_t stride = (size_t)gridDim.x * blockDim.x * 4;

    for (; idx < total; idx += stride) {
        const int col = (int)(idx & (HIDDEN - 1));
        float4 x  = *reinterpret_cast<float4*>(out + idx);
        float4 sm = *reinterpret_cast<const float4*>(bn_acc + col);
        float4 sq = *reinterpret_cast<const float4*>(bn_acc + HIDDEN + col);
        float4 g  = *reinterpret_cast<const float4*>(gamma + col);
        float4 bt = *reinterpret_cast<const float4*>(beta + col);
        float4 hr = *reinterpret_cast<const float4*>(h + idx);

        float4 res;
        {
            float m = sm.x * inv_n; float var = sq.x * inv_n - m * m;
            float v = g.x * (x.x - m) * rsqrtf(var + BN_EPS) + bt.x;
            res.x = fmaxf(v, 0.0f) + hr.x;
        }
        {
            float m = sm.y * inv_n; float var = sq.y * inv_n - m * m;
            float v = g.y * (x.y - m) * rsqrtf(var + BN_EPS) + bt.y;
            res.y = fmaxf(v, 0.0f) + hr.y;
        }
        {
            float m = sm.z * inv_n; float var = sq.z * inv_n - m * m;
            float v = g.z * (x.z - m) * rsqrtf(var + BN_EPS) + bt.z;
            res.z = fmaxf(v, 0.0f) + hr.z;
        }
        {
            float m = sm.w * inv_n; float var = sq.w * inv_n - m * m;
            float v = g.w * (x.w - m) * rsqrtf(var + BN_EPS) + bt.w;
            res.w = fmaxf(v, 0.0f) + hr.w;
        }
        *reinterpret_cast<float4*>(out + idx) = res;
    }
}

extern "C" void kernel_launch(void* const* d_in, const int* in_sizes, int n_in,
                              void* d_out, int out_size, void* d_ws, size_t ws_size,
                              hipStream_t stream)
{
    const float* h          = (const float*)d_in[0];
    const int*   edge_index = (const int*)d_in[1];
    const float* W_l        = (const float*)d_in[2];
    const float* b_l        = (const float*)d_in[3];
    const float* W_r        = (const float*)d_in[4];
    const float* gamma      = (const float*)d_in[5];
    const float* beta       = (const float*)d_in[6];
    float* out = (float*)d_out;

    char* ws = (char*)d_ws;
    int*   cnt   = (int*)ws;                                      // 50000
    int*   slots = cnt + N_NODES;                                 // 50000*64
    float* agg   = (float*)(slots + (size_t)N_NODES * SLOT);      // 50000*128
    unsigned short* WhiG = (unsigned short*)(agg + (size_t)N_NODES * HIDDEN);  // 32768 (16B-aligned)
    unsigned short* WloG = WhiG + 128 * 256;                      // 32768
    float* bn_acc = (float*)(WloG + 128 * 256);                   // 256

    hipMemsetAsync(cnt, 0, (size_t)N_NODES * sizeof(int), stream);

    bin_kernel<<<(N_EDGES + 255) / 256, 256, 0, stream>>>(
        edge_index, W_l, W_r, cnt, slots, WhiG, WloG, bn_acc);

    // 2 feature-half passes x 12500 waves; 4 waves/block -> 6250 blocks
    gather_kernel<<<(2 * (N_NODES / 4) + 3) / 4, 256, 0, stream>>>(h, cnt, slots, agg);

    gemm_kernel<<<(N_NODES + 127) / 128, 256, 0, stream>>>(
        agg, h, WhiG, WloG, b_l, out, bn_acc);

    bn_apply_kernel<<<2048, 256, 0, stream>>>(h, gamma, beta, bn_acc, out);
}